// Round 1
// baseline (263.411 us; speedup 1.0000x reference)
//
#include <hip/hip_runtime.h>

// Bahdanau attention: B=64, T=2048, D=256, U=256, all fp32.
// out = [context (B*D) | attn (B*T)] flat fp32.
#define Bq 64
#define Tq 2048
#define Dq 256
#define Uq 256

#define TT 64   // t-tile per block in K2
#define KK 32   // k-chunk
#define SW 260  // lds w row stride (floats), layout [KK][SW] transposed (k-major)
#define SF 36   // lds f row stride (floats), layout [TT][SF]

// K1: comb[b][u] = dot(hidden[b], w2_w[u]) + w2_b[u] + w1_b[u]
__global__ void k1_comb(const float* __restrict__ hidden,
                        const float* __restrict__ w2_w,
                        const float* __restrict__ w2_b,
                        const float* __restrict__ w1_b,
                        float* __restrict__ comb) {
  int b = blockIdx.x;
  int wave = threadIdx.x >> 6;
  int lane = threadIdx.x & 63;
  int u = blockIdx.y * 4 + wave;
  const float* h = hidden + b * Dq;
  const float* w = w2_w + u * Dq;
  float sum = 0.f;
#pragma unroll
  for (int i = 0; i < Dq; i += 64) sum += h[lane + i] * w[lane + i];
#pragma unroll
  for (int m = 32; m >= 1; m >>= 1) sum += __shfl_xor(sum, m, 64);
  if (lane == 0) comb[b * Uq + u] = sum + w2_b[u] + w1_b[u];
}

// K2: score[b][t] = v_b + sum_u v_w[u] * tanh( feat[b,t,:]·w1_w[u,:] + comb[b][u] )
// block: 256 threads; tile 64 t x 256 u; thread tile 4t x 16u.
// tid = tg*16 + ug ; t = t0 + tg*4 + i ; u = ug*4 + 64*j + component
__global__ __launch_bounds__(256) void k2_score(
    const float* __restrict__ feat, const float* __restrict__ w1_w,
    const float* __restrict__ comb, const float* __restrict__ v_w,
    const float* __restrict__ v_b, float* __restrict__ score) {
  __shared__ float lw[KK * SW];  // w1 chunk, transposed [k][u]
  __shared__ float lf[TT * SF];  // feature tile [t][k]
  const int b = blockIdx.y;
  const int t0 = blockIdx.x * TT;
  const int tid = threadIdx.x;
  const int tg = tid >> 4;
  const int ug = tid & 15;

  float4 acc[4][4];
#pragma unroll
  for (int i = 0; i < 4; ++i)
#pragma unroll
    for (int j = 0; j < 4; ++j) acc[i][j] = make_float4(0.f, 0.f, 0.f, 0.f);

  for (int kk = 0; kk < Dq; kk += KK) {
    // stage features tile: 64 rows x 32 floats, float4 loads
#pragma unroll
    for (int p = 0; p < 2; ++p) {
      int li = tid + 256 * p;  // 0..511
      int row = li >> 3;       // 0..63
      int c4 = li & 7;         // 8 float4 per row
      float4 v = *reinterpret_cast<const float4*>(
          &feat[((size_t)(b * Tq + t0 + row)) * Dq + kk + c4 * 4]);
      *reinterpret_cast<float4*>(&lf[row * SF + c4 * 4]) = v;
    }
    // stage w1 chunk transposed: 256 rows x 32 floats -> lw[k][u]
#pragma unroll
    for (int p = 0; p < 8; ++p) {
      int li = tid + 256 * p;  // 0..2047
      int u = li >> 3;         // 0..255
      int c4 = li & 7;
      float4 v = *reinterpret_cast<const float4*>(&w1_w[u * Dq + kk + c4 * 4]);
      lw[(c4 * 4 + 0) * SW + u] = v.x;
      lw[(c4 * 4 + 1) * SW + u] = v.y;
      lw[(c4 * 4 + 2) * SW + u] = v.z;
      lw[(c4 * 4 + 3) * SW + u] = v.w;
    }
    __syncthreads();

#pragma unroll 2
    for (int k4 = 0; k4 < KK; k4 += 4) {
      float4 fv[4];
#pragma unroll
      for (int i = 0; i < 4; ++i)
        fv[i] = *reinterpret_cast<const float4*>(&lf[(tg * 4 + i) * SF + k4]);
#pragma unroll
      for (int k2 = 0; k2 < 4; ++k2) {
        float4 wv[4];
#pragma unroll
        for (int j = 0; j < 4; ++j)
          wv[j] = *reinterpret_cast<const float4*>(
              &lw[(k4 + k2) * SW + ug * 4 + 64 * j]);
#pragma unroll
        for (int i = 0; i < 4; ++i) {
          float fs = (k2 == 0) ? fv[i].x : (k2 == 1) ? fv[i].y
                    : (k2 == 2) ? fv[i].z : fv[i].w;
#pragma unroll
          for (int j = 0; j < 4; ++j) {
            acc[i][j].x += fs * wv[j].x;
            acc[i][j].y += fs * wv[j].y;
            acc[i][j].z += fs * wv[j].z;
            acc[i][j].w += fs * wv[j].w;
          }
        }
      }
    }
    __syncthreads();
  }

  // epilogue: tanh + v-dot, reduce over the 16 ug lanes
  float sp[4] = {0.f, 0.f, 0.f, 0.f};
#pragma unroll
  for (int j = 0; j < 4; ++j) {
    int u = ug * 4 + 64 * j;
    float4 cb = *reinterpret_cast<const float4*>(&comb[b * Uq + u]);
    float4 vw = *reinterpret_cast<const float4*>(&v_w[u]);
#pragma unroll
    for (int i = 0; i < 4; ++i) {
      sp[i] += vw.x * tanhf(acc[i][j].x + cb.x);
      sp[i] += vw.y * tanhf(acc[i][j].y + cb.y);
      sp[i] += vw.z * tanhf(acc[i][j].z + cb.z);
      sp[i] += vw.w * tanhf(acc[i][j].w + cb.w);
    }
  }
#pragma unroll
  for (int m = 1; m < 16; m <<= 1) {
#pragma unroll
    for (int i = 0; i < 4; ++i) sp[i] += __shfl_xor(sp[i], m, 64);
  }
  if (ug == 0) {
    float vb = v_b[0];
#pragma unroll
    for (int i = 0; i < 4; ++i)
      score[b * Tq + t0 + tg * 4 + i] = sp[i] + vb;
  }
}

// K3: softmax over T per batch, in place. 256 threads, 8 values each.
__global__ void k3_softmax(float* __restrict__ s) {
  int b = blockIdx.x;
  int tid = threadIdx.x;
  const int base = b * Tq;
  float v[8];
  float m = -1e30f;
#pragma unroll
  for (int i = 0; i < 8; ++i) {
    v[i] = s[base + tid + 256 * i];
    m = fmaxf(m, v[i]);
  }
#pragma unroll
  for (int mk = 32; mk >= 1; mk >>= 1) m = fmaxf(m, __shfl_xor(m, mk, 64));
  __shared__ float red[4];
  int wv = tid >> 6, ln = tid & 63;
  if (ln == 0) red[wv] = m;
  __syncthreads();
  m = fmaxf(fmaxf(red[0], red[1]), fmaxf(red[2], red[3]));
  __syncthreads();
  float sum = 0.f;
#pragma unroll
  for (int i = 0; i < 8; ++i) {
    v[i] = __expf(v[i] - m);
    sum += v[i];
  }
#pragma unroll
  for (int mk = 32; mk >= 1; mk >>= 1) sum += __shfl_xor(sum, mk, 64);
  if (ln == 0) red[wv] = sum;
  __syncthreads();
  sum = red[0] + red[1] + red[2] + red[3];
  float inv = 1.f / sum;
#pragma unroll
  for (int i = 0; i < 8; ++i) s[base + tid + 256 * i] = v[i] * inv;
}

// K4a: partial context over a 256-t slice
__global__ void k4_partial(const float* __restrict__ feat,
                           const float* __restrict__ attn,
                           float* __restrict__ part) {
  int b = blockIdx.x;
  int ts = blockIdx.y;
  int d = threadIdx.x;
  const int t0 = ts * 256;
  const float* f = feat + ((size_t)(b * Tq + t0)) * Dq + d;
  const float* a = attn + b * Tq + t0;
  float acc = 0.f;
#pragma unroll 8
  for (int t = 0; t < 256; ++t) acc += a[t] * f[(size_t)t * Dq];
  part[(b * 8 + ts) * Dq + d] = acc;
}

// K4b: reduce the 8 partials
__global__ void k4_reduce(const float* __restrict__ part,
                          float* __restrict__ ctx) {
  int b = blockIdx.x;
  int d = threadIdx.x;
  float s = 0.f;
#pragma unroll
  for (int ts = 0; ts < 8; ++ts) s += part[(b * 8 + ts) * Dq + d];
  ctx[b * Dq + d] = s;
}

extern "C" void kernel_launch(void* const* d_in, const int* in_sizes, int n_in,
                              void* d_out, int out_size, void* d_ws,
                              size_t ws_size, hipStream_t stream) {
  const float* feat   = (const float*)d_in[0];
  const float* hidden = (const float*)d_in[1];
  const float* w1_w   = (const float*)d_in[2];
  const float* w1_b   = (const float*)d_in[3];
  const float* w2_w   = (const float*)d_in[4];
  const float* w2_b   = (const float*)d_in[5];
  const float* v_w    = (const float*)d_in[6];
  const float* v_b    = (const float*)d_in[7];

  float* ctx  = (float*)d_out;           // [B][D]
  float* attn = ctx + Bq * Dq;           // [B][T] (score -> softmax in place)
  float* comb = (float*)d_ws;            // [B][U]
  float* part = comb + Bq * Uq;          // [B][8][D]

  k1_comb<<<dim3(Bq, Uq / 4), 256, 0, stream>>>(hidden, w2_w, w2_b, w1_b, comb);
  k2_score<<<dim3(Tq / TT, Bq), 256, 0, stream>>>(feat, w1_w, comb, v_w, v_b, attn);
  k3_softmax<<<Bq, 256, 0, stream>>>(attn);
  k4_partial<<<dim3(Bq, 8), 256, 0, stream>>>(feat, attn, part);
  k4_reduce<<<Bq, 256, 0, stream>>>(part, ctx);
}

// Round 2
// 123.076 us; speedup vs baseline: 2.1402x; 2.1402x over previous
//
#include <hip/hip_runtime.h>

// Bahdanau attention: B=64, T=2048, D=256, U=256, all fp32 in/out.
// out = [context (B*D) | attn (B*T)] flat fp32.
#define Bq 64
#define Tq 2048
#define Dq 256
#define Uq 256

#define SWB 40  // LDS row stride in bf16 elements (32 data + 8 pad; 80B, 16B-aligned)

typedef __bf16 bf16x8 __attribute__((ext_vector_type(8)));
typedef float f32x4 __attribute__((ext_vector_type(4)));

// split fp32 into truncated-bf16 hi + bf16(lo) residual. a = hi + lo + O(2^-16 |a|)
__device__ inline void split2(float a, unsigned short& h, unsigned short& l) {
  unsigned bits = __float_as_uint(a);
  h = (unsigned short)(bits >> 16);
  float hf = __uint_as_float(bits & 0xffff0000u);
  l = (unsigned short)(__float_as_uint(a - hf) >> 16);
}

// K0: split w1 [U][D] fp32 -> bf16 hi/lo planes in ws
__global__ void k0_split(const float* __restrict__ w1,
                         unsigned short* __restrict__ hi,
                         unsigned short* __restrict__ lo) {
  int i = (blockIdx.x * 256 + threadIdx.x) * 4;
  float4 v = *reinterpret_cast<const float4*>(&w1[i]);
  ushort4 h, l;
  split2(v.x, h.x, l.x);
  split2(v.y, h.y, l.y);
  split2(v.z, h.z, l.z);
  split2(v.w, h.w, l.w);
  *reinterpret_cast<ushort4*>(&hi[i]) = h;
  *reinterpret_cast<ushort4*>(&lo[i]) = l;
}

// K1: comb[b][u] = dot(hidden[b], w2_w[u]) + w2_b[u] + w1_b[u]
__global__ void k1_comb(const float* __restrict__ hidden,
                        const float* __restrict__ w2_w,
                        const float* __restrict__ w2_b,
                        const float* __restrict__ w1_b,
                        float* __restrict__ comb) {
  int b = blockIdx.x;
  int wave = threadIdx.x >> 6;
  int lane = threadIdx.x & 63;
  int u = blockIdx.y * 4 + wave;
  const float* h = hidden + b * Dq;
  const float* w = w2_w + u * Dq;
  float sum = 0.f;
#pragma unroll
  for (int i = 0; i < Dq; i += 64) sum += h[lane + i] * w[lane + i];
#pragma unroll
  for (int m = 32; m >= 1; m >>= 1) sum += __shfl_xor(sum, m, 64);
  if (lane == 0) comb[b * Uq + u] = sum + w2_b[u] + w1_b[u];
}

// K2: score[b][t] = v_b + sum_u v_w[u] * tanh( feat[b,t,:]·w1_w[u,:] + comb[b][u] )
// MFMA 16x16x32 bf16, split-precision (3 mfma per tile pair).
// Block: 256 thr = 4 waves. Tile 64t x 256u, K chunked by 32.
// Wave w owns u-range [w*64, w*64+64): 4m x 4n fragments of 16x16.
__global__ __launch_bounds__(256) void k2_score(
    const float* __restrict__ feat, const unsigned short* __restrict__ w1hi,
    const unsigned short* __restrict__ w1lo, const float* __restrict__ comb,
    const float* __restrict__ v_w, const float* __restrict__ v_b,
    float* __restrict__ score) {
  __shared__ unsigned short lA[2 * 64 * SWB];    // hi plane then lo plane
  __shared__ unsigned short lB[2 * 256 * SWB];   // hi plane then lo plane
  __shared__ float scp[4 * 64];
  const int b = blockIdx.y;
  const int t0 = blockIdx.x * 64;
  const int tid = threadIdx.x;
  const int w = tid >> 6;
  const int l = tid & 63;
  const int fr = l & 15;
  const int g = l >> 4;
  const int ALO = 64 * SWB;
  const int BLO = 256 * SWB;

  f32x4 acc[4][4] = {};

  for (int kc = 0; kc < Dq; kc += 32) {
    __syncthreads();
    // stage A: 64 t-rows x 32 k fp32 -> split bf16 hi/lo
#pragma unroll
    for (int p = 0; p < 2; ++p) {
      int li = tid + 256 * p;  // 0..511
      int row = li >> 3;       // 0..63
      int c4 = li & 7;         // 8 float4 per row
      float4 v = *reinterpret_cast<const float4*>(
          &feat[((size_t)(b * Tq + t0 + row)) * Dq + kc + c4 * 4]);
      ushort4 h, lo4;
      split2(v.x, h.x, lo4.x);
      split2(v.y, h.y, lo4.y);
      split2(v.z, h.z, lo4.z);
      split2(v.w, h.w, lo4.w);
      *reinterpret_cast<ushort4*>(&lA[row * SWB + c4 * 4]) = h;
      *reinterpret_cast<ushort4*>(&lA[ALO + row * SWB + c4 * 4]) = lo4;
    }
    // stage B: 256 u-rows x 32 k bf16 (pre-split), 16B copies
#pragma unroll
    for (int p = 0; p < 4; ++p) {
      int li = tid + 256 * p;  // 0..1023
      int row = li >> 2;       // 0..255
      int c8 = li & 3;         // 4 x (8 bf16) per row
      *reinterpret_cast<float4*>(&lB[row * SWB + c8 * 8]) =
          *reinterpret_cast<const float4*>(&w1hi[row * Dq + kc + c8 * 8]);
      *reinterpret_cast<float4*>(&lB[BLO + row * SWB + c8 * 8]) =
          *reinterpret_cast<const float4*>(&w1lo[row * Dq + kc + c8 * 8]);
    }
    __syncthreads();

    bf16x8 ah[4], al[4], bh[4], bl[4];
#pragma unroll
    for (int mf = 0; mf < 4; ++mf) {
      ah[mf] = *reinterpret_cast<const bf16x8*>(&lA[(mf * 16 + fr) * SWB + g * 8]);
      al[mf] = *reinterpret_cast<const bf16x8*>(&lA[ALO + (mf * 16 + fr) * SWB + g * 8]);
    }
#pragma unroll
    for (int nf = 0; nf < 4; ++nf) {
      int rb = w * 64 + nf * 16 + fr;
      bh[nf] = *reinterpret_cast<const bf16x8*>(&lB[rb * SWB + g * 8]);
      bl[nf] = *reinterpret_cast<const bf16x8*>(&lB[BLO + rb * SWB + g * 8]);
    }
#pragma unroll
    for (int mf = 0; mf < 4; ++mf) {
#pragma unroll
      for (int nf = 0; nf < 4; ++nf) {
        acc[mf][nf] = __builtin_amdgcn_mfma_f32_16x16x32_bf16(
            ah[mf], bh[nf], acc[mf][nf], 0, 0, 0);
        acc[mf][nf] = __builtin_amdgcn_mfma_f32_16x16x32_bf16(
            ah[mf], bl[nf], acc[mf][nf], 0, 0, 0);
        acc[mf][nf] = __builtin_amdgcn_mfma_f32_16x16x32_bf16(
            al[mf], bh[nf], acc[mf][nf], 0, 0, 0);
      }
    }
  }

  // epilogue: tanh + v-dot. acc[mf][nf][r] is (t_local = mf*16 + g*4 + r,
  // u = w*64 + nf*16 + fr)
  float cb[4], vw4[4];
#pragma unroll
  for (int nf = 0; nf < 4; ++nf) {
    int u = w * 64 + nf * 16 + fr;
    cb[nf] = comb[b * Uq + u];
    vw4[nf] = v_w[u];
  }
  float sc[4][4];
#pragma unroll
  for (int mf = 0; mf < 4; ++mf)
#pragma unroll
    for (int r = 0; r < 4; ++r) sc[mf][r] = 0.f;
#pragma unroll
  for (int mf = 0; mf < 4; ++mf)
#pragma unroll
    for (int nf = 0; nf < 4; ++nf)
#pragma unroll
      for (int r = 0; r < 4; ++r)
        sc[mf][r] += vw4[nf] * tanhf(acc[mf][nf][r] + cb[nf]);
  // reduce over the 16 fr lanes (u within this wave's 64)
#pragma unroll
  for (int m = 1; m < 16; m <<= 1)
#pragma unroll
    for (int mf = 0; mf < 4; ++mf)
#pragma unroll
      for (int r = 0; r < 4; ++r) sc[mf][r] += __shfl_xor(sc[mf][r], m, 16);
  if (fr == 0) {
#pragma unroll
    for (int mf = 0; mf < 4; ++mf)
#pragma unroll
      for (int r = 0; r < 4; ++r)
        scp[w * 64 + mf * 16 + g * 4 + r] = sc[mf][r];
  }
  __syncthreads();
  if (tid < 64) {
    float v = scp[tid] + scp[64 + tid] + scp[128 + tid] + scp[192 + tid];
    score[b * Tq + t0 + tid] = v + v_b[0];
  }
}

// K3: softmax over T per batch, in place. 256 threads, 8 values each.
__global__ void k3_softmax(float* __restrict__ s) {
  int b = blockIdx.x;
  int tid = threadIdx.x;
  const int base = b * Tq;
  float v[8];
  float m = -1e30f;
#pragma unroll
  for (int i = 0; i < 8; ++i) {
    v[i] = s[base + tid + 256 * i];
    m = fmaxf(m, v[i]);
  }
#pragma unroll
  for (int mk = 32; mk >= 1; mk >>= 1) m = fmaxf(m, __shfl_xor(m, mk, 64));
  __shared__ float red[4];
  int wv = tid >> 6, ln = tid & 63;
  if (ln == 0) red[wv] = m;
  __syncthreads();
  m = fmaxf(fmaxf(red[0], red[1]), fmaxf(red[2], red[3]));
  __syncthreads();
  float sum = 0.f;
#pragma unroll
  for (int i = 0; i < 8; ++i) {
    v[i] = __expf(v[i] - m);
    sum += v[i];
  }
#pragma unroll
  for (int mk = 32; mk >= 1; mk >>= 1) sum += __shfl_xor(sum, mk, 64);
  if (ln == 0) red[wv] = sum;
  __syncthreads();
  sum = red[0] + red[1] + red[2] + red[3];
  float inv = 1.f / sum;
#pragma unroll
  for (int i = 0; i < 8; ++i) s[base + tid + 256 * i] = v[i] * inv;
}

// K4a: partial context over a 256-t slice
__global__ void k4_partial(const float* __restrict__ feat,
                           const float* __restrict__ attn,
                           float* __restrict__ part) {
  int b = blockIdx.x;
  int ts = blockIdx.y;
  int d = threadIdx.x;
  const int t0 = ts * 256;
  const float* f = feat + ((size_t)(b * Tq + t0)) * Dq + d;
  const float* a = attn + b * Tq + t0;
  float acc = 0.f;
#pragma unroll 8
  for (int t = 0; t < 256; ++t) acc += a[t] * f[(size_t)t * Dq];
  part[(b * 8 + ts) * Dq + d] = acc;
}

// K4b: reduce the 8 partials
__global__ void k4_reduce(const float* __restrict__ part,
                          float* __restrict__ ctx) {
  int b = blockIdx.x;
  int d = threadIdx.x;
  float s = 0.f;
#pragma unroll
  for (int ts = 0; ts < 8; ++ts) s += part[(b * 8 + ts) * Dq + d];
  ctx[b * Dq + d] = s;
}

extern "C" void kernel_launch(void* const* d_in, const int* in_sizes, int n_in,
                              void* d_out, int out_size, void* d_ws,
                              size_t ws_size, hipStream_t stream) {
  const float* feat   = (const float*)d_in[0];
  const float* hidden = (const float*)d_in[1];
  const float* w1_w   = (const float*)d_in[2];
  const float* w1_b   = (const float*)d_in[3];
  const float* w2_w   = (const float*)d_in[4];
  const float* w2_b   = (const float*)d_in[5];
  const float* v_w    = (const float*)d_in[6];
  const float* v_b    = (const float*)d_in[7];

  float* ctx  = (float*)d_out;             // [B][D]
  float* attn = ctx + Bq * Dq;             // [B][T] (score -> softmax in place)
  float* comb = (float*)d_ws;              // [B][U]              64 KB
  float* part = comb + Bq * Uq;            // [B][8][D]           512 KB
  unsigned short* w1hi = (unsigned short*)(part + Bq * 8 * Dq);  // 128 KB
  unsigned short* w1lo = w1hi + Uq * Dq;                          // 128 KB

  k0_split<<<Uq * Dq / 1024, 256, 0, stream>>>(w1_w, w1hi, w1lo);
  k1_comb<<<dim3(Bq, Uq / 4), 256, 0, stream>>>(hidden, w2_w, w2_b, w1_b, comb);
  k2_score<<<dim3(Tq / 64, Bq), 256, 0, stream>>>(feat, w1hi, w1lo, comb, v_w,
                                                  v_b, attn);
  k3_softmax<<<Bq, 256, 0, stream>>>(attn);
  k4_partial<<<dim3(Bq, 8), 256, 0, stream>>>(feat, attn, part);
  k4_reduce<<<Bq, 256, 0, stream>>>(part, ctx);
}

// Round 3
// 98.285 us; speedup vs baseline: 2.6801x; 1.2522x over previous
//
#include <hip/hip_runtime.h>
#include <stdint.h>

// Bahdanau attention: B=64, T=2048, D=256, U=256, all fp32 in/out.
// out = [context (B*D) | attn (B*T)] flat fp32.
#define Bq 64
#define Tq 2048
#define Dq 256
#define Uq 256

// LDS octet-major layout: [k-octet][row][8 bf16], 16B pad per region.
#define ASTRIDE 1040   // bytes per A octet region (64 rows * 16B + 16B pad)
#define APLANE  4160   // 4 octets * ASTRIDE
#define BSTRIDE 4112   // bytes per B octet region (256 rows * 16B + 16B pad)
#define BPLANE  16448  // 4 octets * BSTRIDE

typedef __bf16 bf16x8 __attribute__((ext_vector_type(8)));
typedef float f32x4 __attribute__((ext_vector_type(4)));

// split fp32 into truncated-bf16 hi + bf16(lo) residual. a = hi + lo + O(2^-16 |a|)
__device__ inline void split2(float a, unsigned short& h, unsigned short& l) {
  unsigned bits = __float_as_uint(a);
  h = (unsigned short)(bits >> 16);
  float hf = __uint_as_float(bits & 0xffff0000u);
  l = (unsigned short)(__float_as_uint(a - hf) >> 16);
}

// tanh(x) = 1 - 2/(exp(2x)+1); exp->inf saturates to 1, exp->0 gives -1. ~6 VALU.
__device__ inline float fast_tanh(float x) {
  float e = __expf(2.0f * x);
  return 1.0f - 2.0f * __builtin_amdgcn_rcpf(e + 1.0f);
}

// K0: split w1 [U][D] fp32 -> bf16 hi/lo planes, stored OCTET-MAJOR:
// plane[(k>>3)*U*8 + u*8 + (k&7)]
__global__ void k0_split(const float* __restrict__ w1,
                         unsigned short* __restrict__ hi,
                         unsigned short* __restrict__ lo) {
  int idx = blockIdx.x * 256 + threadIdx.x;
  int i = idx * 4;
  int u = i >> 8;
  int k = i & 255;
  float4 v = *reinterpret_cast<const float4*>(&w1[i]);
  ushort4 h, l;
  split2(v.x, h.x, l.x);
  split2(v.y, h.y, l.y);
  split2(v.z, h.z, l.z);
  split2(v.w, h.w, l.w);
  int dst = (k >> 3) * (Uq * 8) + u * 8 + (k & 7);
  *reinterpret_cast<ushort4*>(&hi[dst]) = h;
  *reinterpret_cast<ushort4*>(&lo[dst]) = l;
}

// K1: comb[b][u] = dot(hidden[b], w2_w[u]) + w2_b[u] + w1_b[u]
__global__ void k1_comb(const float* __restrict__ hidden,
                        const float* __restrict__ w2_w,
                        const float* __restrict__ w2_b,
                        const float* __restrict__ w1_b,
                        float* __restrict__ comb) {
  int b = blockIdx.x;
  int wave = threadIdx.x >> 6;
  int lane = threadIdx.x & 63;
  int u = blockIdx.y * 4 + wave;
  const float* h = hidden + b * Dq;
  const float* w = w2_w + u * Dq;
  float sum = 0.f;
#pragma unroll
  for (int i = 0; i < Dq; i += 64) sum += h[lane + i] * w[lane + i];
#pragma unroll
  for (int m = 32; m >= 1; m >>= 1) sum += __shfl_xor(sum, m, 64);
  if (lane == 0) comb[b * Uq + u] = sum + w2_b[u] + w1_b[u];
}

// K2: score[b][t] = v_b + sum_u v_w[u] * tanh( feat[b,t,:]·w1_w[u,:] + comb[b][u] )
// MFMA 16x16x32 bf16 split-precision. 256 thr = 4 waves; tile 64t x 256u; K by 32.
// Wave w owns u in [w*64, w*64+64): 4m x 4n fragments of 16x16.
__global__ __launch_bounds__(256) void k2_score(
    const float* __restrict__ feat, const unsigned short* __restrict__ w1hi,
    const unsigned short* __restrict__ w1lo, const float* __restrict__ comb,
    const float* __restrict__ v_w, const float* __restrict__ v_b,
    float* __restrict__ score) {
  __shared__ unsigned short lA[2 * APLANE / 2];   // hi plane, lo plane
  __shared__ unsigned short lB[2 * BPLANE / 2];   // hi plane, lo plane
  __shared__ float scp[4 * 64];
  char* cA = (char*)lA;
  char* cB = (char*)lB;
  const int b = blockIdx.y;
  const int t0 = blockIdx.x * 64;
  const int tid = threadIdx.x;
  const int w = tid >> 6;
  const int l = tid & 63;
  const int fr = l & 15;
  const int g = l >> 4;

  f32x4 acc[4][4] = {};

  for (int kc = 0; kc < Dq; kc += 32) {
    __syncthreads();
    // B: DMA hi+lo chunk (octet-major global -> linear LDS regions).
    // 32 wave-loads of 1KB; wave w issues q = w*4..w*4+3 per plane.
#pragma unroll
    for (int p = 0; p < 2; ++p) {
      const unsigned short* gplane = (p ? w1lo : w1hi) + kc * 256;
#pragma unroll
      for (int qq = 0; qq < 4; ++qq) {
        int q = w * 4 + qq;
        const unsigned short* gsrc = gplane + q * 512 + l * 8;
        char* lptr = cB + p * BPLANE + (q >> 2) * BSTRIDE + (q & 3) * 1024;
        __builtin_amdgcn_global_load_lds(
            (const __attribute__((address_space(1))) unsigned int*)gsrc,
            (__attribute__((address_space(3))) unsigned int*)lptr, 16, 0, 0);
      }
    }
    // A: load fp32 features, split to hi/lo, store octet-major.
#pragma unroll
    for (int pp = 0; pp < 2; ++pp) {
      int li = tid + 256 * pp;   // 0..511
      int row = li >> 3;         // 0..63
      int c4 = li & 7;           // float4 column
      float4 v = *reinterpret_cast<const float4*>(
          &feat[((size_t)(b * Tq + t0 + row)) * Dq + kc + c4 * 4]);
      ushort4 h, lo4;
      split2(v.x, h.x, lo4.x);
      split2(v.y, h.y, lo4.y);
      split2(v.z, h.z, lo4.z);
      split2(v.w, h.w, lo4.w);
      int off = (c4 >> 1) * ASTRIDE + row * 16 + (c4 & 1) * 8;
      *reinterpret_cast<ushort4*>(cA + off) = h;
      *reinterpret_cast<ushort4*>(cA + APLANE + off) = lo4;
    }
    __syncthreads();

    bf16x8 ah[4], al[4], bh[4], bl[4];
#pragma unroll
    for (int mf = 0; mf < 4; ++mf) {
      int aoff = g * ASTRIDE + (mf * 16 + fr) * 16;
      ah[mf] = *reinterpret_cast<const bf16x8*>(cA + aoff);
      al[mf] = *reinterpret_cast<const bf16x8*>(cA + APLANE + aoff);
    }
#pragma unroll
    for (int nf = 0; nf < 4; ++nf) {
      int boff = g * BSTRIDE + (w * 64 + nf * 16 + fr) * 16;
      bh[nf] = *reinterpret_cast<const bf16x8*>(cB + boff);
      bl[nf] = *reinterpret_cast<const bf16x8*>(cB + BPLANE + boff);
    }
#pragma unroll
    for (int mf = 0; mf < 4; ++mf) {
#pragma unroll
      for (int nf = 0; nf < 4; ++nf) {
        acc[mf][nf] = __builtin_amdgcn_mfma_f32_16x16x32_bf16(
            ah[mf], bh[nf], acc[mf][nf], 0, 0, 0);
        acc[mf][nf] = __builtin_amdgcn_mfma_f32_16x16x32_bf16(
            ah[mf], bl[nf], acc[mf][nf], 0, 0, 0);
        acc[mf][nf] = __builtin_amdgcn_mfma_f32_16x16x32_bf16(
            al[mf], bh[nf], acc[mf][nf], 0, 0, 0);
      }
    }
  }

  // epilogue: tanh + v-dot. acc[mf][nf][r] is (t_local = mf*16 + g*4 + r,
  // u = w*64 + nf*16 + fr)
  float cb[4], vw4[4];
#pragma unroll
  for (int nf = 0; nf < 4; ++nf) {
    int u = w * 64 + nf * 16 + fr;
    cb[nf] = comb[b * Uq + u];
    vw4[nf] = v_w[u];
  }
  float sc[4][4];
#pragma unroll
  for (int mf = 0; mf < 4; ++mf)
#pragma unroll
    for (int r = 0; r < 4; ++r) sc[mf][r] = 0.f;
#pragma unroll
  for (int mf = 0; mf < 4; ++mf)
#pragma unroll
    for (int nf = 0; nf < 4; ++nf)
#pragma unroll
      for (int r = 0; r < 4; ++r)
        sc[mf][r] += vw4[nf] * fast_tanh(acc[mf][nf][r] + cb[nf]);
  // reduce over the 16 fr lanes (u within this wave's 64)
#pragma unroll
  for (int m = 1; m < 16; m <<= 1)
#pragma unroll
    for (int mf = 0; mf < 4; ++mf)
#pragma unroll
      for (int r = 0; r < 4; ++r) sc[mf][r] += __shfl_xor(sc[mf][r], m, 16);
  if (fr == 0) {
#pragma unroll
    for (int mf = 0; mf < 4; ++mf)
#pragma unroll
      for (int r = 0; r < 4; ++r)
        scp[w * 64 + mf * 16 + g * 4 + r] = sc[mf][r];
  }
  __syncthreads();
  if (tid < 64) {
    float v = scp[tid] + scp[64 + tid] + scp[128 + tid] + scp[192 + tid];
    score[b * Tq + t0 + tid] = v + v_b[0];
  }
}

// K3: softmax over T per batch, in place. 256 threads, 8 values each.
__global__ void k3_softmax(float* __restrict__ s) {
  int b = blockIdx.x;
  int tid = threadIdx.x;
  const int base = b * Tq;
  float v[8];
  float m = -1e30f;
#pragma unroll
  for (int i = 0; i < 8; ++i) {
    v[i] = s[base + tid + 256 * i];
    m = fmaxf(m, v[i]);
  }
#pragma unroll
  for (int mk = 32; mk >= 1; mk >>= 1) m = fmaxf(m, __shfl_xor(m, mk, 64));
  __shared__ float red[4];
  int wv = tid >> 6, ln = tid & 63;
  if (ln == 0) red[wv] = m;
  __syncthreads();
  m = fmaxf(fmaxf(red[0], red[1]), fmaxf(red[2], red[3]));
  __syncthreads();
  float sum = 0.f;
#pragma unroll
  for (int i = 0; i < 8; ++i) {
    v[i] = __expf(v[i] - m);
    sum += v[i];
  }
#pragma unroll
  for (int mk = 32; mk >= 1; mk >>= 1) sum += __shfl_xor(sum, mk, 64);
  if (ln == 0) red[wv] = sum;
  __syncthreads();
  sum = red[0] + red[1] + red[2] + red[3];
  float inv = 1.f / sum;
#pragma unroll
  for (int i = 0; i < 8; ++i) s[base + tid + 256 * i] = v[i] * inv;
}

// K4a: partial context over a 256-t slice
__global__ void k4_partial(const float* __restrict__ feat,
                           const float* __restrict__ attn,
                           float* __restrict__ part) {
  int b = blockIdx.x;
  int ts = blockIdx.y;
  int d = threadIdx.x;
  const int t0 = ts * 256;
  const float* f = feat + ((size_t)(b * Tq + t0)) * Dq + d;
  const float* a = attn + b * Tq + t0;
  float acc = 0.f;
#pragma unroll 8
  for (int t = 0; t < 256; ++t) acc += a[t] * f[(size_t)t * Dq];
  part[(b * 8 + ts) * Dq + d] = acc;
}

// K4b: reduce the 8 partials
__global__ void k4_reduce(const float* __restrict__ part,
                          float* __restrict__ ctx) {
  int b = blockIdx.x;
  int d = threadIdx.x;
  float s = 0.f;
#pragma unroll
  for (int ts = 0; ts < 8; ++ts) s += part[(b * 8 + ts) * Dq + d];
  ctx[b * Dq + d] = s;
}

extern "C" void kernel_launch(void* const* d_in, const int* in_sizes, int n_in,
                              void* d_out, int out_size, void* d_ws,
                              size_t ws_size, hipStream_t stream) {
  const float* feat   = (const float*)d_in[0];
  const float* hidden = (const float*)d_in[1];
  const float* w1_w   = (const float*)d_in[2];
  const float* w1_b   = (const float*)d_in[3];
  const float* w2_w   = (const float*)d_in[4];
  const float* w2_b   = (const float*)d_in[5];
  const float* v_w    = (const float*)d_in[6];
  const float* v_b    = (const float*)d_in[7];

  float* ctx  = (float*)d_out;             // [B][D]
  float* attn = ctx + Bq * Dq;             // [B][T] (score -> softmax in place)
  float* comb = (float*)d_ws;              // [B][U]              64 KB
  float* part = comb + Bq * Uq;            // [B][8][D]           512 KB
  unsigned short* w1hi = (unsigned short*)(part + Bq * 8 * Dq);  // 128 KB
  unsigned short* w1lo = w1hi + Uq * Dq;                          // 128 KB

  k0_split<<<Uq * Dq / 1024, 256, 0, stream>>>(w1_w, w1hi, w1lo);
  k1_comb<<<dim3(Bq, Uq / 4), 256, 0, stream>>>(hidden, w2_w, w2_b, w1_b, comb);
  k2_score<<<dim3(Tq / 64, Bq), 256, 0, stream>>>(feat, w1hi, w1lo, comb, v_w,
                                                  v_b, attn);
  k3_softmax<<<Bq, 256, 0, stream>>>(attn);
  k4_partial<<<dim3(Bq, 8), 256, 0, stream>>>(feat, attn, part);
  k4_reduce<<<Bq, 256, 0, stream>>>(part, ctx);
}